// Round 1
// baseline (24812.982 us; speedup 1.0000x reference)
//
#include <hip/hip_runtime.h>
#include <hip/hip_bf16.h>

// ---------------------------------------------------------------------------
// BiLSTM-CRF on MI355X.
// T=4096, E=1024, H=512 (per dir), 4H=2048, TAGSET=5, START=3, STOP=4.
//
// lstm_kernel (the serial bottleneck): 256 blocks launched, 64 workers
//   (bid%8<2, slot=bid>>3<32) so that under the stride-8 blockIdx->XCD
//   round-robin each direction's 32 blocks share ONE XCD (= one L2).
//   h handoff is dual-path:
//     fast:  plain global_store/load with sc0 (bypass L1, served by the
//            shared per-XCD L2, ~200cy) into an 8MB/dir buffer that
//            aliases the dead xbf/Wfb/Wbb workspace regions.
//     slow:  agent-scope relaxed atomics (L2-bypass, L3/HBM) -- the
//            original protocol, kept as correctness fallback + feats input.
//   Adaptive kslow: probe slow every iteration until the fast path first
//   succeeds, then only every 16th iteration. In fast mode the slow store
//   and the X prefetch are issued AFTER the poll succeeds so the poll's
//   vmcnt(0) never waits on a ~900cy HBM store ack (vmcnt retires in
//   order); in slow mode the store is issued at production time exactly
//   like the baseline, which keeps the fallback deadlock-free.
//   Correctness does not depend on block->XCD placement: any topology
//   resolves through the slow path (plus a bounded 8-iteration escape
//   for pending stores in mixed topologies).
// ---------------------------------------------------------------------------

#define T_LEN 4096
#define EDIM  1024
#define HID   512
#define G4    2048   // 4*HID

typedef short short8 __attribute__((ext_vector_type(8)));
typedef float f32x4  __attribute__((ext_vector_type(4)));

__device__ __forceinline__ float bf16_to_f32(unsigned bits) {
  return __uint_as_float(bits << 16);
}
__device__ __forceinline__ unsigned bf16rne(float f) {
  unsigned u = __float_as_uint(f);
  return (u + 0x7fffu + ((u >> 16) & 1u)) >> 16;   // RNE, NaN not expected
}

// 64-lane sum via DPP on the VALU pipe (no LDS port). Result in lane 63.
__device__ __forceinline__ float wave_sum64(float x) {
  int t;
  t = __builtin_amdgcn_update_dpp(0, __float_as_int(x), 0x111, 0xf, 0xf, true); x += __int_as_float(t); // shr1
  t = __builtin_amdgcn_update_dpp(0, __float_as_int(x), 0x112, 0xf, 0xf, true); x += __int_as_float(t); // shr2
  t = __builtin_amdgcn_update_dpp(0, __float_as_int(x), 0x114, 0xf, 0xf, true); x += __int_as_float(t); // shr4
  t = __builtin_amdgcn_update_dpp(0, __float_as_int(x), 0x118, 0xf, 0xf, true); x += __int_as_float(t); // shr8
  t = __builtin_amdgcn_update_dpp(0, __float_as_int(x), 0x142, 0xf, 0xf, true); x += __int_as_float(t); // bcast15
  t = __builtin_amdgcn_update_dpp(0, __float_as_int(x), 0x143, 0xf, 0xf, true); x += __int_as_float(t); // bcast31
  return x;
}

__device__ __forceinline__ float fsig(float x) {
  return __builtin_amdgcn_rcpf(1.f + __builtin_amdgcn_exp2f(-1.44269504f * x));
}
__device__ __forceinline__ float ftanh(float x) {
  return 1.f - 2.f * __builtin_amdgcn_rcpf(1.f + __builtin_amdgcn_exp2f(2.88539008f * x));
}

// --------------------------- gather + convert ------------------------------
__global__ __launch_bounds__(256) void gather_kernel(
    const int* __restrict__ sent, const float* __restrict__ embed,
    unsigned short* __restrict__ xbf)
{
  const int t = blockIdx.x;
  const int tok = sent[t];
  const int e = threadIdx.x * 4;
  const float4 v = *(const float4*)(embed + (size_t)tok * EDIM + e);
  uint2 o;
  o.x = bf16rne(v.x) | (bf16rne(v.y) << 16);
  o.y = bf16rne(v.z) | (bf16rne(v.w) << 16);
  *(uint2*)(xbf + (size_t)t * EDIM + e) = o;
}

__global__ __launch_bounds__(256) void convw_kernel(
    const float* __restrict__ Wf, const float* __restrict__ Wb,
    unsigned short* __restrict__ of, unsigned short* __restrict__ ob)
{
  const float* src = blockIdx.z ? Wb : Wf;
  unsigned short* dst = blockIdx.z ? ob : of;
  const size_t idx = (size_t)blockIdx.x * 2048 + (size_t)threadIdx.x * 8;
  const float4 a = *(const float4*)(src + idx);
  const float4 b = *(const float4*)(src + idx + 4);
  uint4 o;
  o.x = bf16rne(a.x) | (bf16rne(a.y) << 16);
  o.y = bf16rne(a.z) | (bf16rne(a.w) << 16);
  o.z = bf16rne(b.x) | (bf16rne(b.y) << 16);
  o.w = bf16rne(b.z) | (bf16rne(b.w) << 16);
  *(uint4*)(dst + idx) = o;
}

__global__ __launch_bounds__(512) void inith_kernel(
    const float* __restrict__ h0, unsigned* __restrict__ hcF,
    unsigned* __restrict__ hcB)
{
  unsigned* hc = blockIdx.x ? hcB : hcF;
  const int j = threadIdx.x;
  hc[j] = bf16rne(h0[blockIdx.x * HID + j]);   // tag (high 16) = 0
}

// --------------------------- X = x @ W_ih^T + b ----------------------------
__global__ __launch_bounds__(256) void gemm_x_kernel(
    const unsigned short* __restrict__ xbf,
    const unsigned short* __restrict__ Wfb, const unsigned short* __restrict__ Wbb,
    const float* __restrict__ biasF, const float* __restrict__ biasB,
    float* __restrict__ Xf, float* __restrict__ Xb)
{
  const int zz = blockIdx.z;
  const unsigned short* Bp = zz ? Wbb : Wfb;
  const float* bias = zz ? biasB : biasF;
  float* C = zz ? Xb : Xf;
  const int n0 = blockIdx.x * 64;
  const int m0 = blockIdx.y * 64;
  __shared__ unsigned short As[64][40];
  __shared__ unsigned short Bs[64][40];
  const int tid = threadIdx.x;
  const int wv = tid >> 6, lane = tid & 63;
  const int moff = (wv >> 1) * 32, noff = (wv & 1) * 32;
  const int lrow = tid >> 2, lseg = (tid & 3) * 8;
  const int fr = lane & 15;
  const int fk = (lane >> 4) * 8;
  f32x4 acc[2][2];
#pragma unroll
  for (int i = 0; i < 2; i++)
#pragma unroll
    for (int j = 0; j < 2; j++) acc[i][j] = (f32x4){0.f, 0.f, 0.f, 0.f};

  for (int k0 = 0; k0 < EDIM; k0 += 32) {
    const uint4 av = *(const uint4*)(xbf + (size_t)(m0 + lrow) * EDIM + k0 + lseg);
    const uint4 bv = *(const uint4*)(Bp  + (size_t)(n0 + lrow) * EDIM + k0 + lseg);
    *(uint4*)&As[lrow][lseg] = av;
    *(uint4*)&Bs[lrow][lseg] = bv;
    __syncthreads();
    short8 af[2], bg[2];
#pragma unroll
    for (int i = 0; i < 2; i++) af[i] = *(const short8*)&As[moff + i * 16 + fr][fk];
#pragma unroll
    for (int j = 0; j < 2; j++) bg[j] = *(const short8*)&Bs[noff + j * 16 + fr][fk];
#pragma unroll
    for (int i = 0; i < 2; i++)
#pragma unroll
      for (int j = 0; j < 2; j++)
        acc[i][j] = __builtin_amdgcn_mfma_f32_16x16x32_bf16(af[i], bg[j], acc[i][j], 0, 0, 0);
    __syncthreads();
  }
#pragma unroll
  for (int i = 0; i < 2; i++)
#pragma unroll
    for (int j = 0; j < 2; j++) {
      const int col = n0 + noff + j * 16 + fr;
      const float bv = bias[col];
#pragma unroll
      for (int r = 0; r < 4; r++) {
        const int row = m0 + moff + i * 16 + (lane >> 4) * 4 + r;
        C[(size_t)row * G4 + col] = acc[i][j][r] + bv;
      }
    }
}

// ------------------------------- recurrence --------------------------------
// 256 blocks x 512 threads; workers: dir = bid&7 (<2), slot = bid>>3 (<32).
// Under stride-8 bid->XCD round-robin, dir0 lives on XCD0 and dir1 on XCD1,
// so the sc0 fast path resolves through one shared L2.
__global__ __launch_bounds__(512) void lstm_kernel(
    const float* __restrict__ WhhF, const float* __restrict__ WhhB,
    const float* __restrict__ Xf, const float* __restrict__ Xb,
    const float* __restrict__ c0,
    unsigned* __restrict__ hcF, unsigned* __restrict__ hcB,
    unsigned* __restrict__ hfF, unsigned* __restrict__ hfB)
{
  const int bid = blockIdx.x;
  const int dir = bid & 7;
  const int slot = bid >> 3;
  if (dir >= 2 || slot >= 32) return;

  const float* Whh = dir ? WhhB : WhhF;
  const float* X   = dir ? Xb : Xf;
  unsigned* hcomm  = dir ? hcB : hcF;
  unsigned* hfast  = dir ? hfB : hfF;

  const int tid = threadIdx.x;
  const int w = tid >> 6;             // wave 0..7
  const int c = tid & 63;             // lane
  const int jw = slot * 16 + 2 * w;   // wave's even-aligned j pair

  __shared__ float hl[2][HID];
  __shared__ int flg[2][8];

  // weights in VGPRs: rows r = gate*2 + p (p = j offset in pair)
  float4 wA[8], wB[8];
#pragma unroll
  for (int g = 0; g < 4; ++g)
#pragma unroll
    for (int p = 0; p < 2; ++p) {
      const float* row = Whh + (size_t)(g * HID + jw + p) * HID;
      wA[g * 2 + p] = *(const float4*)(row + 4 * c);
      wB[g * 2 + p] = *(const float4*)(row + 256 + 4 * c);
    }

  if (tid < 16) ((int*)flg)[tid] = -1;
  __syncthreads();

  float cs0 = 0.f, cs1 = 0.f;
  float2 xc[4], xn[4];
#pragma unroll
  for (int g = 0; g < 4; ++g) { xc[g] = make_float2(0.f, 0.f); xn[g] = make_float2(0.f, 0.f); }
  if (c == 63) {
    cs0 = c0[dir * HID + jw];
    cs1 = c0[dir * HID + jw + 1];
    const int xrow0 = dir ? (T_LEN - 1) : 0;
#pragma unroll
    for (int g = 0; g < 4; ++g)
      xc[g] = *(const float2*)(X + (size_t)xrow0 * G4 + g * HID + jw);
  }

  int kslow = 1;                       // 1 = slow-probe every iter (fallback)
  bool spend = false;                  // lane-uniform: slow store pending?
  unsigned long long pk_pend = 0;      // lane63: pending slow-store payload

  for (int s = 0; s < T_LEN; ++s) {
    const unsigned want = (unsigned)s;
    float* hbuf = hl[s & 1];
    volatile int* fl = flg[s & 1];
    const int base = (w << 6) + c;
    unsigned* spst = hcomm + (size_t)s * HID + jw;   // pending slow target (slot s)

    unsigned v = 0;

    // phase P: poll for slot s (fast sc0/L2 path + agent-scope fallback)
    if (s == 0) {
      const unsigned* ap = hcomm + base;
      for (;;) {
        v = __hip_atomic_load(ap, __ATOMIC_RELAXED, __HIP_MEMORY_SCOPE_AGENT);
        if (__all((int)((v >> 16) == want))) break;
      }
    } else {
      const unsigned* fp = hfast + (size_t)(s - 1) * HID + base;
      const unsigned* sp = hcomm + (size_t)s * HID + base;
      int it = 0, ms = 0;
      bool fast_hit = false;
      for (;;) {
        ++it;
        unsigned vf;
        if (++ms >= kslow) {
          ms = 0;
          asm volatile("global_load_dword %0, %1, off sc0" : "=v"(vf) : "v"(fp) : "memory");
          unsigned vs = __hip_atomic_load(sp, __ATOMIC_RELAXED, __HIP_MEMORY_SCOPE_AGENT);
          asm volatile("s_waitcnt vmcnt(0)" ::: "memory");
          __builtin_amdgcn_sched_barrier(0);
          if (__all((int)((vf >> 16) == want))) { v = vf; fast_hit = true; break; }
          const unsigned vm = ((vf >> 16) == want) ? vf : vs;
          if (__all((int)((vm >> 16) == want))) { v = vm; break; }
        } else {
          asm volatile("global_load_dword %0, %1, off sc0" : "=v"(vf) : "v"(fp) : "memory");
          asm volatile("s_waitcnt vmcnt(0)" ::: "memory");
          __builtin_amdgcn_sched_barrier(0);
          if (__all((int)((vf >> 16) == want))) { v = vf; fast_hit = true; break; }
        }
        // bounded escape: in mixed topologies a pending slow store must not
        // wait on our own progress forever
        if (spend && it >= 8) {
          if (c == 63)
            __hip_atomic_store((unsigned long long*)spst, pk_pend,
                               __ATOMIC_RELAXED, __HIP_MEMORY_SCOPE_AGENT);
          spend = false;
        }
      }
      kslow = fast_hit ? 16 : 1;
    }

    // post-poll background issues (off the poll's vmcnt(0) critical path):
    // pending slow store for slot s, then next step's X prefetch
    if (spend) {
      if (c == 63)
        __hip_atomic_store((unsigned long long*)spst, pk_pend,
                           __ATOMIC_RELAXED, __HIP_MEMORY_SCOPE_AGENT);
      spend = false;
    }
    if (c == 63 && s + 1 < T_LEN) {
      const int xrow = dir ? (T_LEN - 2 - s) : (s + 1);
#pragma unroll
      for (int g = 0; g < 4; ++g)
        xn[g] = *(const float2*)(X + (size_t)xrow * G4 + g * HID + jw);
    }

    // LDS relay: commit own chunk, raise flag, wait all 8 flags
    hbuf[base] = bf16_to_f32(v & 0xffffu);
    asm volatile("s_waitcnt lgkmcnt(0)" ::: "memory");  // chunk committed
    if (c == 0) fl[w] = (int)s;
    for (;;) {
      const int fv = fl[c & 7];
      if (__all(fv == (int)s)) break;
    }

    // phase C: dense conflict-free LDS reads + 64 FMA + DPP reduce
    const float4 hA = *(const float4*)&hbuf[4 * c];
    const float4 hB = *(const float4*)&hbuf[256 + 4 * c];
    float sum[8];
#pragma unroll
    for (int r = 0; r < 8; ++r) {
      float sr = wA[r].x * hA.x + wA[r].y * hA.y + wA[r].z * hA.z + wA[r].w * hA.w
               + wB[r].x * hB.x + wB[r].y * hB.y + wB[r].z * hB.z + wB[r].w * hB.w;
      sum[r] = wave_sum64(sr);
    }

    if (c == 63) {
      const float i0 = fsig (sum[0] + xc[0].x), i1 = fsig (sum[1] + xc[0].y);
      const float f0 = fsig (sum[2] + xc[1].x), f1 = fsig (sum[3] + xc[1].y);
      const float g0 = ftanh(sum[4] + xc[2].x), g1 = ftanh(sum[5] + xc[2].y);
      const float o0 = fsig (sum[6] + xc[3].x), o1 = fsig (sum[7] + xc[3].y);
      cs0 = f0 * cs0 + i0 * g0;
      cs1 = f1 * cs1 + i1 * g1;
      const float h0v = o0 * ftanh(cs0);
      const float h1v = o1 * ftanh(cs1);
      const unsigned tag = (unsigned)(s + 1) << 16;
      const unsigned long long pk =
          ((unsigned long long)(tag | bf16rne(h1v)) << 32) | (tag | bf16rne(h0v));
      // fast copy: slot s+1 lives at hfast + s*HID (slots 1..T_LEN)
      unsigned* fdst = hfast + (size_t)s * HID + jw;
      asm volatile("global_store_dwordx2 %0, %1, off sc0" :: "v"(fdst), "v"(pk) : "memory");
      pk_pend = pk;
      if (kslow == 1) {
        // slow mode: issue agent-scope store NOW (baseline protocol,
        // deadlock-free fallback)
        __hip_atomic_store((unsigned long long*)(hcomm + (size_t)(s + 1) * HID + jw), pk,
                           __ATOMIC_RELAXED, __HIP_MEMORY_SCOPE_AGENT);
      }
    }
    spend = (kslow != 1);   // fast mode: defer slow store past next poll
#pragma unroll
    for (int g = 0; g < 4; ++g) xc[g] = xn[g];
  }

  // drain the final pending slow store (slot T_LEN) -- feats reads it
  if (spend && c == 63)
    __hip_atomic_store((unsigned long long*)(hcomm + (size_t)T_LEN * HID + jw), pk_pend,
                       __ATOMIC_RELAXED, __HIP_MEMORY_SCOPE_AGENT);
}

// ------------------------------- features ----------------------------------
__global__ __launch_bounds__(320) void feats_kernel(
    const unsigned* __restrict__ hcF, const unsigned* __restrict__ hcB,
    const float* __restrict__ Wout, const float* __restrict__ bout,
    float* __restrict__ feats)
{
  const int t = blockIdx.x;
  const int tag = threadIdx.x >> 6;   // 0..4, one wave per tag
  const int lane = threadIdx.x & 63;
  const unsigned* hf = hcF + (size_t)(t + 1) * HID;
  const unsigned* hb = hcB + (size_t)(T_LEN - t) * HID;
  float sum = 0.f;
  for (int e = lane; e < HID; e += 64) {
    sum += Wout[tag * 1024 + e]       * bf16_to_f32(hf[e] & 0xffffu);
    sum += Wout[tag * 1024 + 512 + e] * bf16_to_f32(hb[e] & 0xffffu);
  }
#pragma unroll
  for (int m = 1; m < 64; m <<= 1) sum += __shfl_xor(sum, m, 64);
  if (lane == 0) feats[t * 5 + tag] = sum + bout[tag];
}

// ------------------------------- Viterbi -----------------------------------
__device__ __forceinline__ unsigned map_compose(unsigned a, unsigned b) {
  unsigned r = 0;
#pragma unroll
  for (int i = 0; i < 5; ++i) {
    const unsigned gi = (b >> (3 * i)) & 7u;
    r |= ((a >> (3 * gi)) & 7u) << (3 * i);
  }
  return r;
}

__global__ __launch_bounds__(64) void viterbi_kernel(
    const float* __restrict__ feats, const float* __restrict__ trans,
    float* __restrict__ out)
{
  __shared__ float fe[2][2560];
  __shared__ unsigned char bpb[5][T_LEN];
  const int lane = threadIdx.x;
  const int n = lane >> 3, p = lane & 7;
  const bool act = (n < 5) && (p < 5);
  const int nn = (n < 5) ? n : 0;
  const float tr = act ? trans[n * 5 + p] : -3.0e38f;
  float fvp = (p == 3) ? 0.f : -10000.f;

  for (int i = lane; i < 2560; i += 64) fe[0][i] = feats[i];
  __syncthreads();

  for (int ch = 0; ch < 8; ++ch) {
    const int buf = ch & 1;
    float pf[40];
    if (ch < 7) {
#pragma unroll
      for (int i = 0; i < 40; ++i)
        pf[i] = feats[(ch + 1) * 2560 + i * 64 + lane];
    }
    for (int tt = 0; tt < 512; ++tt) {
      const int t = ch * 512 + tt;
      float s = act ? (fvp + tr) : -3.0e38f;
      float bm = s; int bp_ = p;
#pragma unroll
      for (int d = 1; d < 8; d <<= 1) {
        const float os = __shfl_xor(bm, d, 64);
        const int   op = __shfl_xor(bp_, d, 64);
        if (os > bm || (os == bm && op < bp_)) { bm = os; bp_ = op; }
      }
      const float fvn = bm + fe[buf][tt * 5 + nn];
      if (p == 0 && n < 5) bpb[n][t] = (unsigned char)bp_;
      fvp = __shfl(fvn, p * 8, 64);
    }
    __syncthreads();
    if (ch < 7) {
#pragma unroll
      for (int i = 0; i < 40; ++i) fe[buf ^ 1][i * 64 + lane] = pf[i];
    }
    __syncthreads();
  }

  float tv = (lane < 5) ? (fvp + trans[4 * 5 + lane]) : -3.0e38f;
  int bl = lane;
#pragma unroll
  for (int d = 1; d < 8; d <<= 1) {
    const float ov = __shfl_xor(tv, d, 64);
    const int   ol = __shfl_xor(bl, d, 64);
    if (ov > tv || (ov == tv && ol < bl)) { tv = ov; bl = ol; }
  }
  const float score = __shfl(tv, 0, 64);
  const int best = __shfl(bl, 0, 64);
  if (lane == 0) out[0] = score;

  const unsigned IDENT = 0u | (1u << 3) | (2u << 6) | (3u << 9) | (4u << 12);
  const int lo = lane * 64;
  unsigned msave[64];
  unsigned comp = IDENT;
#pragma unroll
  for (int tt = 0; tt < 64; ++tt) {
    const int t = lo + tt;
    unsigned mt;
    if (t == 0) mt = IDENT;
    else
      mt = (unsigned)bpb[0][t] | ((unsigned)bpb[1][t] << 3) |
           ((unsigned)bpb[2][t] << 6) | ((unsigned)bpb[3][t] << 9) |
           ((unsigned)bpb[4][t] << 12);
    msave[tt] = mt;
    comp = map_compose(comp, mt);
  }
  unsigned inc = comp;
#pragma unroll
  for (int d = 1; d < 64; d <<= 1) {
    const unsigned other = __shfl_down(inc, d, 64);
    const unsigned comb = map_compose(inc, other);
    if (lane + d < 64) inc = comb;
  }
  unsigned exc = __shfl_down(inc, 1, 64);
  if (lane == 63) exc = IDENT;

  int y = (int)((exc >> (3 * best)) & 7u);
  out[1 + lo + 63] = (float)y;
#pragma unroll
  for (int tt = 63; tt >= 0; --tt) {
    const int t = lo + tt;
    if (t == 0) break;
    y = (int)((msave[tt] >> (3 * y)) & 7u);
    out[1 + t - 1] = (float)y;
  }
}

// ------------------------------- launcher ----------------------------------
extern "C" void kernel_launch(void* const* d_in, const int* in_sizes, int n_in,
                              void* d_out, int out_size, void* d_ws, size_t ws_size,
                              hipStream_t stream) {
  const int*   sent   = (const int*)d_in[0];
  const float* embed  = (const float*)d_in[1];
  const float* W_ih_f = (const float*)d_in[2];
  const float* W_hh_f = (const float*)d_in[3];
  const float* b_f    = (const float*)d_in[4];
  const float* W_ih_b = (const float*)d_in[5];
  const float* W_hh_b = (const float*)d_in[6];
  const float* b_b    = (const float*)d_in[7];
  const float* h0     = (const float*)d_in[8];
  const float* c0     = (const float*)d_in[9];
  const float* W_out  = (const float*)d_in[10];
  const float* b_out  = (const float*)d_in[11];
  const float* trans  = (const float*)d_in[12];

  char* ws = (char*)d_ws;
  float*          Xf    = (float*)(ws + 0);
  float*          Xb    = (float*)(ws + 33554432);
  unsigned short* xbf   = (unsigned short*)(ws + 67108864);
  unsigned short* Wfb   = (unsigned short*)(ws + 75497472);
  unsigned short* Wbb   = (unsigned short*)(ws + 79691776);
  unsigned*       hcF   = (unsigned*)(ws + 83886080);
  unsigned*       hcB   = (unsigned*)(ws + 92276736);
  float*          feats = (float*)(ws + 100667392);
  // fast-path h buffers alias regions dead after gemm_x (xbf / Wfb+Wbb),
  // 8MB each = 4096 slots x 512 dwords; rewritten by gather/convw every
  // launch, so no stale tag can survive across launches.
  unsigned*       hfF   = (unsigned*)(ws + 67108864);
  unsigned*       hfB   = (unsigned*)(ws + 75497472);
  float*          out   = (float*)d_out;

  gather_kernel<<<T_LEN, 256, 0, stream>>>(sent, embed, xbf);
  convw_kernel<<<dim3(1024, 1, 2), 256, 0, stream>>>(W_ih_f, W_ih_b, Wfb, Wbb);
  inith_kernel<<<2, 512, 0, stream>>>(h0, hcF, hcB);
  gemm_x_kernel<<<dim3(32, 64, 2), 256, 0, stream>>>(xbf, Wfb, Wbb, b_f, b_b, Xf, Xb);
  lstm_kernel<<<256, 512, 0, stream>>>(W_hh_f, W_hh_b, Xf, Xb, c0, hcF, hcB, hfF, hfB);
  feats_kernel<<<T_LEN, 320, 0, stream>>>(hcF, hcB, W_out, b_out, feats);
  viterbi_kernel<<<1, 64, 0, stream>>>(feats, trans, out);
}

// Round 3
// 14457.306 us; speedup vs baseline: 1.7163x; 1.7163x over previous
//
#include <hip/hip_runtime.h>
#include <hip/hip_bf16.h>

// ---------------------------------------------------------------------------
// BiLSTM-CRF on MI355X.
// T=4096, E=1024, H=512 (per dir), 4H=2048, TAGSET=5, START=3, STOP=4.
//   lstm_kernel (the serial bottleneck): 64 blocks x 512 thr (32/dir).
//   Wave w polls ONLY its own 64-dword chunk of h slot s (data==flag),
//   using a 3-deep PIPELINED poll: three loads in flight, counted
//   s_waitcnt vmcnt(2) so each check waits only for the oldest load.
//   Detection granularity ~150-200cy instead of ~1 full load latency,
//   shrinking the max-over-32-blocks straggler term that dominated the
//   6000cy/step baseline. s_sleep(1) per rotation throttles L3 traffic.
//   Pipeline regs stay live across the step (empty "+v" asm) so in-flight
//   loads never write a reallocated VGPR; sched_barrier(0) after each
//   counted wait stops the compiler hoisting the checks (rule #18).
//   SAFETY: a 512-iteration guard drains vmcnt and falls back to the
//   verified baseline serial poll, so any flaw in the counted-wait
//   reasoning degrades to baseline speed instead of hanging.
//   Rest of the protocol identical to the verified 10.2ms baseline:
//   agent-scope tagged stores, LDS flag relay, DPP reduce, lane63 gates.
// ---------------------------------------------------------------------------

#define T_LEN 4096
#define EDIM  1024
#define HID   512
#define G4    2048   // 4*HID

typedef short short8 __attribute__((ext_vector_type(8)));
typedef float f32x4  __attribute__((ext_vector_type(4)));

__device__ __forceinline__ float bf16_to_f32(unsigned bits) {
  return __uint_as_float(bits << 16);
}
__device__ __forceinline__ unsigned bf16rne(float f) {
  unsigned u = __float_as_uint(f);
  return (u + 0x7fffu + ((u >> 16) & 1u)) >> 16;   // RNE, NaN not expected
}

// 64-lane sum via DPP on the VALU pipe (no LDS port). Result in lane 63.
__device__ __forceinline__ float wave_sum64(float x) {
  int t;
  t = __builtin_amdgcn_update_dpp(0, __float_as_int(x), 0x111, 0xf, 0xf, true); x += __int_as_float(t); // shr1
  t = __builtin_amdgcn_update_dpp(0, __float_as_int(x), 0x112, 0xf, 0xf, true); x += __int_as_float(t); // shr2
  t = __builtin_amdgcn_update_dpp(0, __float_as_int(x), 0x114, 0xf, 0xf, true); x += __int_as_float(t); // shr4
  t = __builtin_amdgcn_update_dpp(0, __float_as_int(x), 0x118, 0xf, 0xf, true); x += __int_as_float(t); // shr8
  t = __builtin_amdgcn_update_dpp(0, __float_as_int(x), 0x142, 0xf, 0xf, true); x += __int_as_float(t); // bcast15
  t = __builtin_amdgcn_update_dpp(0, __float_as_int(x), 0x143, 0xf, 0xf, true); x += __int_as_float(t); // bcast31
  return x;
}

__device__ __forceinline__ float fsig(float x) {
  return __builtin_amdgcn_rcpf(1.f + __builtin_amdgcn_exp2f(-1.44269504f * x));
}
__device__ __forceinline__ float ftanh(float x) {
  return 1.f - 2.f * __builtin_amdgcn_rcpf(1.f + __builtin_amdgcn_exp2f(2.88539008f * x));
}

// --------------------------- gather + convert ------------------------------
__global__ __launch_bounds__(256) void gather_kernel(
    const int* __restrict__ sent, const float* __restrict__ embed,
    unsigned short* __restrict__ xbf)
{
  const int t = blockIdx.x;
  const int tok = sent[t];
  const int e = threadIdx.x * 4;
  const float4 v = *(const float4*)(embed + (size_t)tok * EDIM + e);
  uint2 o;
  o.x = bf16rne(v.x) | (bf16rne(v.y) << 16);
  o.y = bf16rne(v.z) | (bf16rne(v.w) << 16);
  *(uint2*)(xbf + (size_t)t * EDIM + e) = o;
}

__global__ __launch_bounds__(256) void convw_kernel(
    const float* __restrict__ Wf, const float* __restrict__ Wb,
    unsigned short* __restrict__ of, unsigned short* __restrict__ ob)
{
  const float* src = blockIdx.z ? Wb : Wf;
  unsigned short* dst = blockIdx.z ? ob : of;
  const size_t idx = (size_t)blockIdx.x * 2048 + (size_t)threadIdx.x * 8;
  const float4 a = *(const float4*)(src + idx);
  const float4 b = *(const float4*)(src + idx + 4);
  uint4 o;
  o.x = bf16rne(a.x) | (bf16rne(a.y) << 16);
  o.y = bf16rne(a.z) | (bf16rne(a.w) << 16);
  o.z = bf16rne(b.x) | (bf16rne(b.y) << 16);
  o.w = bf16rne(b.z) | (bf16rne(b.w) << 16);
  *(uint4*)(dst + idx) = o;
}

__global__ __launch_bounds__(512) void inith_kernel(
    const float* __restrict__ h0, unsigned* __restrict__ hcF,
    unsigned* __restrict__ hcB)
{
  unsigned* hc = blockIdx.x ? hcB : hcF;
  const int j = threadIdx.x;
  hc[j] = bf16rne(h0[blockIdx.x * HID + j]);   // tag (high 16) = 0
}

// --------------------------- X = x @ W_ih^T + b ----------------------------
__global__ __launch_bounds__(256) void gemm_x_kernel(
    const unsigned short* __restrict__ xbf,
    const unsigned short* __restrict__ Wfb, const unsigned short* __restrict__ Wbb,
    const float* __restrict__ biasF, const float* __restrict__ biasB,
    float* __restrict__ Xf, float* __restrict__ Xb)
{
  const int zz = blockIdx.z;
  const unsigned short* Bp = zz ? Wbb : Wfb;
  const float* bias = zz ? biasB : biasF;
  float* C = zz ? Xb : Xf;
  const int n0 = blockIdx.x * 64;
  const int m0 = blockIdx.y * 64;
  __shared__ unsigned short As[64][40];
  __shared__ unsigned short Bs[64][40];
  const int tid = threadIdx.x;
  const int wv = tid >> 6, lane = tid & 63;
  const int moff = (wv >> 1) * 32, noff = (wv & 1) * 32;
  const int lrow = tid >> 2, lseg = (tid & 3) * 8;
  const int fr = lane & 15;
  const int fk = (lane >> 4) * 8;
  f32x4 acc[2][2];
#pragma unroll
  for (int i = 0; i < 2; i++)
#pragma unroll
    for (int j = 0; j < 2; j++) acc[i][j] = (f32x4){0.f, 0.f, 0.f, 0.f};

  for (int k0 = 0; k0 < EDIM; k0 += 32) {
    const uint4 av = *(const uint4*)(xbf + (size_t)(m0 + lrow) * EDIM + k0 + lseg);
    const uint4 bv = *(const uint4*)(Bp  + (size_t)(n0 + lrow) * EDIM + k0 + lseg);
    *(uint4*)&As[lrow][lseg] = av;
    *(uint4*)&Bs[lrow][lseg] = bv;
    __syncthreads();
    short8 af[2], bg[2];
#pragma unroll
    for (int i = 0; i < 2; i++) af[i] = *(const short8*)&As[moff + i * 16 + fr][fk];
#pragma unroll
    for (int j = 0; j < 2; j++) bg[j] = *(const short8*)&Bs[noff + j * 16 + fr][fk];
#pragma unroll
    for (int i = 0; i < 2; i++)
#pragma unroll
      for (int j = 0; j < 2; j++)
        acc[i][j] = __builtin_amdgcn_mfma_f32_16x16x32_bf16(af[i], bg[j], acc[i][j], 0, 0, 0);
    __syncthreads();
  }
#pragma unroll
  for (int i = 0; i < 2; i++)
#pragma unroll
    for (int j = 0; j < 2; j++) {
      const int col = n0 + noff + j * 16 + fr;
      const float bv = bias[col];
#pragma unroll
      for (int r = 0; r < 4; r++) {
        const int row = m0 + moff + i * 16 + (lane >> 4) * 4 + r;
        C[(size_t)row * G4 + col] = acc[i][j][r] + bv;
      }
    }
}

// ------------------------------- recurrence --------------------------------
// 64 blocks x 512 threads. Block b: dir=b>>5, owns j in [16*(b&31), +16).
// Wave w owns j pair {j0+2w, j0+2w+1}: 8 gate rows, K=512 across 64 lanes.
// Pipelined 3-deep poll of own 64-dword chunk; LDS flag relay; no s_barrier.
__global__ __launch_bounds__(512) void lstm_kernel(
    const float* __restrict__ WhhF, const float* __restrict__ WhhB,
    const float* __restrict__ Xf, const float* __restrict__ Xb,
    const float* __restrict__ c0,
    unsigned* __restrict__ hcF, unsigned* __restrict__ hcB)
{
  const int b = blockIdx.x;
  const int dir = b >> 5;
  const float* Whh = dir ? WhhB : WhhF;
  const float* X   = dir ? Xb : Xf;
  unsigned* hcomm  = dir ? hcB : hcF;

  const int tid = threadIdx.x;
  const int w = tid >> 6;             // wave 0..7
  const int c = tid & 63;             // lane
  const int jw = (b & 31) * 16 + 2 * w;  // wave's even-aligned j pair

  __shared__ float hl[2][HID];
  __shared__ int flg[2][8];

  // weights in VGPRs: rows r = gate*2 + p (p = j offset in pair)
  float4 wA[8], wB[8];
#pragma unroll
  for (int g = 0; g < 4; ++g)
#pragma unroll
    for (int p = 0; p < 2; ++p) {
      const float* row = Whh + (size_t)(g * HID + jw + p) * HID;
      wA[g * 2 + p] = *(const float4*)(row + 4 * c);
      wB[g * 2 + p] = *(const float4*)(row + 256 + 4 * c);
    }

  if (tid < 16) ((int*)flg)[tid] = -1;
  __syncthreads();

  float cs0 = 0.f, cs1 = 0.f;
  float2 xc[4], xn[4];
#pragma unroll
  for (int g = 0; g < 4; ++g) { xc[g] = make_float2(0.f, 0.f); xn[g] = make_float2(0.f, 0.f); }
  if (c == 63) {
    cs0 = c0[dir * HID + jw];
    cs1 = c0[dir * HID + jw + 1];
    const int xrow0 = dir ? (T_LEN - 1) : 0;
#pragma unroll
    for (int g = 0; g < 4; ++g)
      xc[g] = *(const float2*)(X + (size_t)xrow0 * G4 + g * HID + jw);
  }

  // persistent poll-pipeline registers (must outlive in-flight loads)
  unsigned p0 = 0, p1 = 0, p2 = 0;

  for (int s = 0; s < T_LEN; ++s) {
    const unsigned want = (unsigned)s;
    float* hbuf = hl[s & 1];
    volatile int* fl = flg[s & 1];
    const unsigned* ap = hcomm + (size_t)s * HID + (w << 6) + c;
    unsigned v = 0;
    bool got = false;

    // phase P: 3-deep pipelined poll. vmcnt(2) waits only for the oldest
    // in-flight load (in-order retirement makes counted waits conservative
    // even with compiler loads/stores in flight). Guard falls back to the
    // verified baseline serial poll after 512 rotations.
    asm volatile("global_load_dword %0, %1, off sc0 sc1" : "=v"(p0) : "v"(ap) : "memory");
    asm volatile("global_load_dword %0, %1, off sc0 sc1" : "=v"(p1) : "v"(ap) : "memory");
    asm volatile("global_load_dword %0, %1, off sc0 sc1" : "=v"(p2) : "v"(ap) : "memory");
    for (int guard = 0; !got; ) {
      asm volatile("s_waitcnt vmcnt(2)" ::: "memory");
      __builtin_amdgcn_sched_barrier(0);
      if (__all((int)((p0 >> 16) == want))) { v = p0; break; }
      asm volatile("global_load_dword %0, %1, off sc0 sc1" : "=v"(p0) : "v"(ap) : "memory");
      asm volatile("s_waitcnt vmcnt(2)" ::: "memory");
      __builtin_amdgcn_sched_barrier(0);
      if (__all((int)((p1 >> 16) == want))) { v = p1; break; }
      asm volatile("global_load_dword %0, %1, off sc0 sc1" : "=v"(p1) : "v"(ap) : "memory");
      asm volatile("s_waitcnt vmcnt(2)" ::: "memory");
      __builtin_amdgcn_sched_barrier(0);
      if (__all((int)((p2 >> 16) == want))) { v = p2; break; }
      asm volatile("global_load_dword %0, %1, off sc0 sc1" : "=v"(p2) : "v"(ap) : "memory");
      __builtin_amdgcn_s_sleep(1);   // throttle L3 poll traffic
      if (++guard >= 512) {          // safety net: baseline serial poll
        asm volatile("s_waitcnt vmcnt(0)" ::: "memory");
        __builtin_amdgcn_sched_barrier(0);
        for (;;) {
          const unsigned vv = __hip_atomic_load(ap, __ATOMIC_RELAXED, __HIP_MEMORY_SCOPE_AGENT);
          if (__all((int)((vv >> 16) == want))) { v = vv; got = true; break; }
        }
      }
    }
    // keep pipeline regs live: in-flight leftovers may still write them
    asm volatile("" : "+v"(p0), "+v"(p1), "+v"(p2));

    // post-poll X prefetch (never baggage ahead of the first poll check)
    if (c == 63 && s + 1 < T_LEN) {
      const int xrow = dir ? (T_LEN - 2 - s) : (s + 1);
#pragma unroll
      for (int g = 0; g < 4; ++g)
        xn[g] = *(const float2*)(X + (size_t)xrow * G4 + g * HID + jw);
    }

    // LDS relay: commit own chunk, raise flag, wait all 8 flags
    hbuf[(w << 6) + c] = bf16_to_f32(v & 0xffffu);
    asm volatile("s_waitcnt lgkmcnt(0)" ::: "memory");  // chunk committed
    if (c == 0) fl[w] = (int)s;
    for (;;) {
      const int fv = fl[c & 7];
      if (__all(fv == (int)s)) break;
    }

    // phase C: dense conflict-free LDS reads + 64 FMA + DPP reduce
    const float4 hA = *(const float4*)&hbuf[4 * c];
    const float4 hB = *(const float4*)&hbuf[256 + 4 * c];
    float sum[8];
#pragma unroll
    for (int r = 0; r < 8; ++r) {
      float sr = wA[r].x * hA.x + wA[r].y * hA.y + wA[r].z * hA.z + wA[r].w * hA.w
               + wB[r].x * hB.x + wB[r].y * hB.y + wB[r].z * hB.z + wB[r].w * hB.w;
      sum[r] = wave_sum64(sr);
    }

    if (c == 63) {
      const float i0 = fsig (sum[0] + xc[0].x), i1 = fsig (sum[1] + xc[0].y);
      const float f0 = fsig (sum[2] + xc[1].x), f1 = fsig (sum[3] + xc[1].y);
      const float g0 = ftanh(sum[4] + xc[2].x), g1 = ftanh(sum[5] + xc[2].y);
      const float o0 = fsig (sum[6] + xc[3].x), o1 = fsig (sum[7] + xc[3].y);
      cs0 = f0 * cs0 + i0 * g0;
      cs1 = f1 * cs1 + i1 * g1;
      const float h0v = o0 * ftanh(cs0);
      const float h1v = o1 * ftanh(cs1);
      const unsigned tag = (unsigned)(s + 1) << 16;
      const unsigned long long pk =
          ((unsigned long long)(tag | bf16rne(h1v)) << 32) | (tag | bf16rne(h0v));
      __hip_atomic_store((unsigned long long*)(hcomm + (size_t)(s + 1) * HID + jw), pk,
                         __ATOMIC_RELAXED, __HIP_MEMORY_SCOPE_AGENT);
    }
#pragma unroll
    for (int g = 0; g < 4; ++g) xc[g] = xn[g];
    asm volatile("" : "+v"(p0), "+v"(p1), "+v"(p2));  // live through the step
  }
  asm volatile("s_waitcnt vmcnt(0)" ::: "memory");  // drain leftovers
}

// ------------------------------- features ----------------------------------
__global__ __launch_bounds__(320) void feats_kernel(
    const unsigned* __restrict__ hcF, const unsigned* __restrict__ hcB,
    const float* __restrict__ Wout, const float* __restrict__ bout,
    float* __restrict__ feats)
{
  const int t = blockIdx.x;
  const int tag = threadIdx.x >> 6;   // 0..4, one wave per tag
  const int lane = threadIdx.x & 63;
  const unsigned* hf = hcF + (size_t)(t + 1) * HID;
  const unsigned* hb = hcB + (size_t)(T_LEN - t) * HID;
  float sum = 0.f;
  for (int e = lane; e < HID; e += 64) {
    sum += Wout[tag * 1024 + e]       * bf16_to_f32(hf[e] & 0xffffu);
    sum += Wout[tag * 1024 + 512 + e] * bf16_to_f32(hb[e] & 0xffffu);
  }
#pragma unroll
  for (int m = 1; m < 64; m <<= 1) sum += __shfl_xor(sum, m, 64);
  if (lane == 0) feats[t * 5 + tag] = sum + bout[tag];
}

// ------------------------------- Viterbi -----------------------------------
__device__ __forceinline__ unsigned map_compose(unsigned a, unsigned b) {
  unsigned r = 0;
#pragma unroll
  for (int i = 0; i < 5; ++i) {
    const unsigned gi = (b >> (3 * i)) & 7u;
    r |= ((a >> (3 * gi)) & 7u) << (3 * i);
  }
  return r;
}

__global__ __launch_bounds__(64) void viterbi_kernel(
    const float* __restrict__ feats, const float* __restrict__ trans,
    float* __restrict__ out)
{
  __shared__ float fe[2][2560];
  __shared__ unsigned char bpb[5][T_LEN];
  const int lane = threadIdx.x;
  const int n = lane >> 3, p = lane & 7;
  const bool act = (n < 5) && (p < 5);
  const int nn = (n < 5) ? n : 0;
  const float tr = act ? trans[n * 5 + p] : -3.0e38f;
  float fvp = (p == 3) ? 0.f : -10000.f;

  for (int i = lane; i < 2560; i += 64) fe[0][i] = feats[i];
  __syncthreads();

  for (int ch = 0; ch < 8; ++ch) {
    const int buf = ch & 1;
    float pf[40];
    if (ch < 7) {
#pragma unroll
      for (int i = 0; i < 40; ++i)
        pf[i] = feats[(ch + 1) * 2560 + i * 64 + lane];
    }
    for (int tt = 0; tt < 512; ++tt) {
      const int t = ch * 512 + tt;
      float s = act ? (fvp + tr) : -3.0e38f;
      float bm = s; int bp_ = p;
#pragma unroll
      for (int d = 1; d < 8; d <<= 1) {
        const float os = __shfl_xor(bm, d, 64);
        const int   op = __shfl_xor(bp_, d, 64);
        if (os > bm || (os == bm && op < bp_)) { bm = os; bp_ = op; }
      }
      const float fvn = bm + fe[buf][tt * 5 + nn];
      if (p == 0 && n < 5) bpb[n][t] = (unsigned char)bp_;
      fvp = __shfl(fvn, p * 8, 64);
    }
    __syncthreads();
    if (ch < 7) {
#pragma unroll
      for (int i = 0; i < 40; ++i) fe[buf ^ 1][i * 64 + lane] = pf[i];
    }
    __syncthreads();
  }

  float tv = (lane < 5) ? (fvp + trans[4 * 5 + lane]) : -3.0e38f;
  int bl = lane;
#pragma unroll
  for (int d = 1; d < 8; d <<= 1) {
    const float ov = __shfl_xor(tv, d, 64);
    const int   ol = __shfl_xor(bl, d, 64);
    if (ov > tv || (ov == tv && ol < bl)) { tv = ov; bl = ol; }
  }
  const float score = __shfl(tv, 0, 64);
  const int best = __shfl(bl, 0, 64);
  if (lane == 0) out[0] = score;

  const unsigned IDENT = 0u | (1u << 3) | (2u << 6) | (3u << 9) | (4u << 12);
  const int lo = lane * 64;
  unsigned msave[64];
  unsigned comp = IDENT;
#pragma unroll
  for (int tt = 0; tt < 64; ++tt) {
    const int t = lo + tt;
    unsigned mt;
    if (t == 0) mt = IDENT;
    else
      mt = (unsigned)bpb[0][t] | ((unsigned)bpb[1][t] << 3) |
           ((unsigned)bpb[2][t] << 6) | ((unsigned)bpb[3][t] << 9) |
           ((unsigned)bpb[4][t] << 12);
    msave[tt] = mt;
    comp = map_compose(comp, mt);
  }
  unsigned inc = comp;
#pragma unroll
  for (int d = 1; d < 64; d <<= 1) {
    const unsigned other = __shfl_down(inc, d, 64);
    const unsigned comb = map_compose(inc, other);
    if (lane + d < 64) inc = comb;
  }
  unsigned exc = __shfl_down(inc, 1, 64);
  if (lane == 63) exc = IDENT;

  int y = (int)((exc >> (3 * best)) & 7u);
  out[1 + lo + 63] = (float)y;
#pragma unroll
  for (int tt = 63; tt >= 0; --tt) {
    const int t = lo + tt;
    if (t == 0) break;
    y = (int)((msave[tt] >> (3 * y)) & 7u);
    out[1 + t - 1] = (float)y;
  }
}

// ------------------------------- launcher ----------------------------------
extern "C" void kernel_launch(void* const* d_in, const int* in_sizes, int n_in,
                              void* d_out, int out_size, void* d_ws, size_t ws_size,
                              hipStream_t stream) {
  const int*   sent   = (const int*)d_in[0];
  const float* embed  = (const float*)d_in[1];
  const float* W_ih_f = (const float*)d_in[2];
  const float* W_hh_f = (const float*)d_in[3];
  const float* b_f    = (const float*)d_in[4];
  const float* W_ih_b = (const float*)d_in[5];
  const float* W_hh_b = (const float*)d_in[6];
  const float* b_b    = (const float*)d_in[7];
  const float* h0     = (const float*)d_in[8];
  const float* c0     = (const float*)d_in[9];
  const float* W_out  = (const float*)d_in[10];
  const float* b_out  = (const float*)d_in[11];
  const float* trans  = (const float*)d_in[12];

  char* ws = (char*)d_ws;
  float*          Xf    = (float*)(ws + 0);
  float*          Xb    = (float*)(ws + 33554432);
  unsigned short* xbf   = (unsigned short*)(ws + 67108864);
  unsigned short* Wfb   = (unsigned short*)(ws + 75497472);
  unsigned short* Wbb   = (unsigned short*)(ws + 79691776);
  unsigned*       hcF   = (unsigned*)(ws + 83886080);
  unsigned*       hcB   = (unsigned*)(ws + 92276736);
  float*          feats = (float*)(ws + 100667392);
  float*          out   = (float*)d_out;

  gather_kernel<<<T_LEN, 256, 0, stream>>>(sent, embed, xbf);
  convw_kernel<<<dim3(1024, 1, 2), 256, 0, stream>>>(W_ih_f, W_ih_b, Wfb, Wbb);
  inith_kernel<<<2, 512, 0, stream>>>(h0, hcF, hcB);
  gemm_x_kernel<<<dim3(32, 64, 2), 256, 0, stream>>>(xbf, Wfb, Wbb, b_f, b_b, Xf, Xb);
  lstm_kernel<<<64, 512, 0, stream>>>(W_hh_f, W_hh_b, Xf, Xb, c0, hcF, hcB);
  feats_kernel<<<T_LEN, 320, 0, stream>>>(hcF, hcB, W_out, b_out, feats);
  viterbi_kernel<<<1, 64, 0, stream>>>(feats, trans, out);
}

// Round 4
// 9509.711 us; speedup vs baseline: 2.6092x; 1.5203x over previous
//
#include <hip/hip_runtime.h>
#include <hip/hip_bf16.h>

// ---------------------------------------------------------------------------
// BiLSTM-CRF on MI355X.
// T=4096, E=1024, H=512 (per dir), 4H=2048, TAGSET=5, START=3, STOP=4.
//   lstm_kernel (the serial bottleneck): 64 blocks x 576 thr (9 waves).
//   Protocol = the verified 10.2ms baseline (agent-scope tagged h slots,
//   per-wave 64-dword chunk poll, LDS flag relay, DPP reduce, lane63 gates)
//   with TWO changes:
//     1) dedicated STORER wave (w==8): compute waves stage gate outputs in
//        LDS; the storer issues the block's 64B line as one coalesced
//        agent-scope store. Compute waves issue NO global stores, so the
//        poll's vmcnt(0) no longer drains a ~1000cy store ack every step
//        (stores count in vmcnt and retire in order).
//     2) early poll sample: one slot-(s+1) load + the X prefetch are issued
//        BEFORE phase C; their latency elapses under compute, so the first
//        tag check is often free. Miss => verbatim baseline serial poll.
//   No extra poll traffic (R3 showed the coherence point is service-rate
//   limited on the hot lines; adding traffic lengthens queues).
// ---------------------------------------------------------------------------

#define T_LEN 4096
#define EDIM  1024
#define HID   512
#define G4    2048   // 4*HID

typedef short short8 __attribute__((ext_vector_type(8)));
typedef float f32x4  __attribute__((ext_vector_type(4)));

__device__ __forceinline__ float bf16_to_f32(unsigned bits) {
  return __uint_as_float(bits << 16);
}
__device__ __forceinline__ unsigned bf16rne(float f) {
  unsigned u = __float_as_uint(f);
  return (u + 0x7fffu + ((u >> 16) & 1u)) >> 16;   // RNE, NaN not expected
}

// 64-lane sum via DPP on the VALU pipe (no LDS port). Result in lane 63.
__device__ __forceinline__ float wave_sum64(float x) {
  int t;
  t = __builtin_amdgcn_update_dpp(0, __float_as_int(x), 0x111, 0xf, 0xf, true); x += __int_as_float(t); // shr1
  t = __builtin_amdgcn_update_dpp(0, __float_as_int(x), 0x112, 0xf, 0xf, true); x += __int_as_float(t); // shr2
  t = __builtin_amdgcn_update_dpp(0, __float_as_int(x), 0x114, 0xf, 0xf, true); x += __int_as_float(t); // shr4
  t = __builtin_amdgcn_update_dpp(0, __float_as_int(x), 0x118, 0xf, 0xf, true); x += __int_as_float(t); // shr8
  t = __builtin_amdgcn_update_dpp(0, __float_as_int(x), 0x142, 0xf, 0xf, true); x += __int_as_float(t); // bcast15
  t = __builtin_amdgcn_update_dpp(0, __float_as_int(x), 0x143, 0xf, 0xf, true); x += __int_as_float(t); // bcast31
  return x;
}

__device__ __forceinline__ float fsig(float x) {
  return __builtin_amdgcn_rcpf(1.f + __builtin_amdgcn_exp2f(-1.44269504f * x));
}
__device__ __forceinline__ float ftanh(float x) {
  return 1.f - 2.f * __builtin_amdgcn_rcpf(1.f + __builtin_amdgcn_exp2f(2.88539008f * x));
}

// --------------------------- gather + convert ------------------------------
__global__ __launch_bounds__(256) void gather_kernel(
    const int* __restrict__ sent, const float* __restrict__ embed,
    unsigned short* __restrict__ xbf)
{
  const int t = blockIdx.x;
  const int tok = sent[t];
  const int e = threadIdx.x * 4;
  const float4 v = *(const float4*)(embed + (size_t)tok * EDIM + e);
  uint2 o;
  o.x = bf16rne(v.x) | (bf16rne(v.y) << 16);
  o.y = bf16rne(v.z) | (bf16rne(v.w) << 16);
  *(uint2*)(xbf + (size_t)t * EDIM + e) = o;
}

__global__ __launch_bounds__(256) void convw_kernel(
    const float* __restrict__ Wf, const float* __restrict__ Wb,
    unsigned short* __restrict__ of, unsigned short* __restrict__ ob)
{
  const float* src = blockIdx.z ? Wb : Wf;
  unsigned short* dst = blockIdx.z ? ob : of;
  const size_t idx = (size_t)blockIdx.x * 2048 + (size_t)threadIdx.x * 8;
  const float4 a = *(const float4*)(src + idx);
  const float4 b = *(const float4*)(src + idx + 4);
  uint4 o;
  o.x = bf16rne(a.x) | (bf16rne(a.y) << 16);
  o.y = bf16rne(a.z) | (bf16rne(a.w) << 16);
  o.z = bf16rne(b.x) | (bf16rne(b.y) << 16);
  o.w = bf16rne(b.z) | (bf16rne(b.w) << 16);
  *(uint4*)(dst + idx) = o;
}

__global__ __launch_bounds__(512) void inith_kernel(
    const float* __restrict__ h0, unsigned* __restrict__ hcF,
    unsigned* __restrict__ hcB)
{
  unsigned* hc = blockIdx.x ? hcB : hcF;
  const int j = threadIdx.x;
  hc[j] = bf16rne(h0[blockIdx.x * HID + j]);   // tag (high 16) = 0
}

// --------------------------- X = x @ W_ih^T + b ----------------------------
__global__ __launch_bounds__(256) void gemm_x_kernel(
    const unsigned short* __restrict__ xbf,
    const unsigned short* __restrict__ Wfb, const unsigned short* __restrict__ Wbb,
    const float* __restrict__ biasF, const float* __restrict__ biasB,
    float* __restrict__ Xf, float* __restrict__ Xb)
{
  const int zz = blockIdx.z;
  const unsigned short* Bp = zz ? Wbb : Wfb;
  const float* bias = zz ? biasB : biasF;
  float* C = zz ? Xb : Xf;
  const int n0 = blockIdx.x * 64;
  const int m0 = blockIdx.y * 64;
  __shared__ unsigned short As[64][40];
  __shared__ unsigned short Bs[64][40];
  const int tid = threadIdx.x;
  const int wv = tid >> 6, lane = tid & 63;
  const int moff = (wv >> 1) * 32, noff = (wv & 1) * 32;
  const int lrow = tid >> 2, lseg = (tid & 3) * 8;
  const int fr = lane & 15;
  const int fk = (lane >> 4) * 8;
  f32x4 acc[2][2];
#pragma unroll
  for (int i = 0; i < 2; i++)
#pragma unroll
    for (int j = 0; j < 2; j++) acc[i][j] = (f32x4){0.f, 0.f, 0.f, 0.f};

  for (int k0 = 0; k0 < EDIM; k0 += 32) {
    const uint4 av = *(const uint4*)(xbf + (size_t)(m0 + lrow) * EDIM + k0 + lseg);
    const uint4 bv = *(const uint4*)(Bp  + (size_t)(n0 + lrow) * EDIM + k0 + lseg);
    *(uint4*)&As[lrow][lseg] = av;
    *(uint4*)&Bs[lrow][lseg] = bv;
    __syncthreads();
    short8 af[2], bg[2];
#pragma unroll
    for (int i = 0; i < 2; i++) af[i] = *(const short8*)&As[moff + i * 16 + fr][fk];
#pragma unroll
    for (int j = 0; j < 2; j++) bg[j] = *(const short8*)&Bs[noff + j * 16 + fr][fk];
#pragma unroll
    for (int i = 0; i < 2; i++)
#pragma unroll
      for (int j = 0; j < 2; j++)
        acc[i][j] = __builtin_amdgcn_mfma_f32_16x16x32_bf16(af[i], bg[j], acc[i][j], 0, 0, 0);
    __syncthreads();
  }
#pragma unroll
  for (int i = 0; i < 2; i++)
#pragma unroll
    for (int j = 0; j < 2; j++) {
      const int col = n0 + noff + j * 16 + fr;
      const float bv = bias[col];
#pragma unroll
      for (int r = 0; r < 4; r++) {
        const int row = m0 + moff + i * 16 + (lane >> 4) * 4 + r;
        C[(size_t)row * G4 + col] = acc[i][j][r] + bv;
      }
    }
}

// ------------------------------- recurrence --------------------------------
// 64 blocks x 576 threads. Block b: dir=b>>5, owns j in [16*(b&31), +16).
// Waves 0..7 compute (wave w owns j pair {j0+2w, j0+2w+1}); wave 8 is the
// dedicated storer (keeps global stores out of compute waves' vmcnt).
__global__ __launch_bounds__(576) void lstm_kernel(
    const float* __restrict__ WhhF, const float* __restrict__ WhhB,
    const float* __restrict__ Xf, const float* __restrict__ Xb,
    const float* __restrict__ c0,
    unsigned* __restrict__ hcF, unsigned* __restrict__ hcB)
{
  const int b = blockIdx.x;
  const int dir = b >> 5;
  const float* Whh = dir ? WhhB : WhhF;
  const float* X   = dir ? Xb : Xf;
  unsigned* hcomm  = dir ? hcB : hcF;

  const int tid = threadIdx.x;
  const int w = tid >> 6;             // wave 0..8
  const int c = tid & 63;             // lane
  const int blk16 = (b & 31) * 16;    // block's j base
  const int jw = blk16 + 2 * w;       // wave's even-aligned j pair (w<8)

  __shared__ float hl[2][HID];
  __shared__ int flg[2][8];
  __shared__ unsigned hstage[2][16];  // staged tagged h dwords (block's line)
  __shared__ int gflg[2][8];          // gate-done flags for the storer

  if (tid < 16) ((int*)flg)[tid] = -1;
  else if (tid < 32) ((int*)gflg)[tid - 16] = -1;
  __syncthreads();

  if (w == 8) {
    // ---- dedicated storer wave: wait 8 gate flags, store the 64B line ----
    for (int s = 0; s < T_LEN; ++s) {
      const int par = (s + 1) & 1;
      volatile int* gfl = gflg[par];
      for (;;) {
        const int fv = gfl[c & 7];
        if (__all(fv == (int)s)) break;
      }
      asm volatile("" ::: "memory");
      if (c < 16) {
        const unsigned val = ((volatile unsigned*)hstage[par])[c];
        __hip_atomic_store(hcomm + (size_t)(s + 1) * HID + blk16 + c, val,
                           __ATOMIC_RELAXED, __HIP_MEMORY_SCOPE_AGENT);
      }
    }
    asm volatile("s_waitcnt vmcnt(0)" ::: "memory");  // drain before endpgm
    return;
  }

  // ---- compute waves ----
  // weights in VGPRs: rows r = gate*2 + p (p = j offset in pair)
  float4 wA[8], wB[8];
#pragma unroll
  for (int g = 0; g < 4; ++g)
#pragma unroll
    for (int p = 0; p < 2; ++p) {
      const float* row = Whh + (size_t)(g * HID + jw + p) * HID;
      wA[g * 2 + p] = *(const float4*)(row + 4 * c);
      wB[g * 2 + p] = *(const float4*)(row + 256 + 4 * c);
    }

  float cs0 = 0.f, cs1 = 0.f;
  float2 xc[4], xn[4];
#pragma unroll
  for (int g = 0; g < 4; ++g) { xc[g] = make_float2(0.f, 0.f); xn[g] = make_float2(0.f, 0.f); }
  if (c == 63) {
    cs0 = c0[dir * HID + jw];
    cs1 = c0[dir * HID + jw + 1];
    const int xrow0 = dir ? (T_LEN - 1) : 0;
#pragma unroll
    for (int g = 0; g < 4; ++g)
      xc[g] = *(const float2*)(X + (size_t)xrow0 * G4 + g * HID + jw);
  }

  unsigned pre = 0;   // early poll sample for the next slot (live across steps)

  for (int s = 0; s < T_LEN; ++s) {
    const unsigned want = (unsigned)s;
    float* hbuf = hl[s & 1];
    volatile int* fl = flg[s & 1];
    const unsigned* ap = hcomm + (size_t)s * HID + (w << 6) + c;
    unsigned v;

    // phase P: check the early sample first (its latency elapsed under the
    // previous compute phase); miss -> verbatim baseline serial poll.
    asm volatile("s_waitcnt vmcnt(0)" ::: "memory");
    __builtin_amdgcn_sched_barrier(0);
    if (s > 0 && __all((int)((pre >> 16) == want))) {
      v = pre;
    } else {
      for (;;) {
        v = __hip_atomic_load(ap, __ATOMIC_RELAXED, __HIP_MEMORY_SCOPE_AGENT);
        if (__all((int)((v >> 16) == want))) break;
      }
    }

    // LDS relay: commit own chunk, raise flag, wait all 8 flags
    hbuf[(w << 6) + c] = bf16_to_f32(v & 0xffffu);
    asm volatile("s_waitcnt lgkmcnt(0)" ::: "memory");  // chunk committed
    if (c == 0) fl[w] = (int)s;
    for (;;) {
      const int fv = fl[c & 7];
      if (__all(fv == (int)s)) break;
    }
    asm volatile("" ::: "memory");

    // early issues for step s+1: poll sample + X prefetch (drain under C)
    if (s + 1 < T_LEN) {
      const unsigned* apn = ap + HID;
      asm volatile("global_load_dword %0, %1, off sc0 sc1" : "=v"(pre) : "v"(apn) : "memory");
      if (c == 63) {
        const int xrow = dir ? (T_LEN - 2 - s) : (s + 1);
#pragma unroll
        for (int g = 0; g < 4; ++g)
          xn[g] = *(const float2*)(X + (size_t)xrow * G4 + g * HID + jw);
      }
    }

    // phase C: dense conflict-free LDS reads + 64 FMA + DPP reduce
    const float4 hA = *(const float4*)&hbuf[4 * c];
    const float4 hB = *(const float4*)&hbuf[256 + 4 * c];
    float sum[8];
#pragma unroll
    for (int r = 0; r < 8; ++r) {
      float sr = wA[r].x * hA.x + wA[r].y * hA.y + wA[r].z * hA.z + wA[r].w * hA.w
               + wB[r].x * hB.x + wB[r].y * hB.y + wB[r].z * hB.z + wB[r].w * hB.w;
      sum[r] = wave_sum64(sr);
    }

    if (c == 63) {
      const float i0 = fsig (sum[0] + xc[0].x), i1 = fsig (sum[1] + xc[0].y);
      const float f0 = fsig (sum[2] + xc[1].x), f1 = fsig (sum[3] + xc[1].y);
      const float g0 = ftanh(sum[4] + xc[2].x), g1 = ftanh(sum[5] + xc[2].y);
      const float o0 = fsig (sum[6] + xc[3].x), o1 = fsig (sum[7] + xc[3].y);
      cs0 = f0 * cs0 + i0 * g0;
      cs1 = f1 * cs1 + i1 * g1;
      const float h0v = o0 * ftanh(cs0);
      const float h1v = o1 * ftanh(cs1);
      const unsigned tag = (unsigned)(s + 1) << 16;
      // stage to LDS; the storer wave issues the global store
      volatile unsigned* st = hstage[(s + 1) & 1];
      st[2 * w]     = tag | bf16rne(h0v);
      st[2 * w + 1] = tag | bf16rne(h1v);
      asm volatile("s_waitcnt lgkmcnt(0)" ::: "memory");  // data before flag
      ((volatile int*)gflg[(s + 1) & 1])[w] = (int)s;
    }
#pragma unroll
    for (int g = 0; g < 4; ++g) xc[g] = xn[g];
    asm volatile("" : "+v"(pre));   // keep early-sample reg live across step
  }
  asm volatile("s_waitcnt vmcnt(0)" ::: "memory");  // drain leftovers
}

// ------------------------------- features ----------------------------------
__global__ __launch_bounds__(320) void feats_kernel(
    const unsigned* __restrict__ hcF, const unsigned* __restrict__ hcB,
    const float* __restrict__ Wout, const float* __restrict__ bout,
    float* __restrict__ feats)
{
  const int t = blockIdx.x;
  const int tag = threadIdx.x >> 6;   // 0..4, one wave per tag
  const int lane = threadIdx.x & 63;
  const unsigned* hf = hcF + (size_t)(t + 1) * HID;
  const unsigned* hb = hcB + (size_t)(T_LEN - t) * HID;
  float sum = 0.f;
  for (int e = lane; e < HID; e += 64) {
    sum += Wout[tag * 1024 + e]       * bf16_to_f32(hf[e] & 0xffffu);
    sum += Wout[tag * 1024 + 512 + e] * bf16_to_f32(hb[e] & 0xffffu);
  }
#pragma unroll
  for (int m = 1; m < 64; m <<= 1) sum += __shfl_xor(sum, m, 64);
  if (lane == 0) feats[t * 5 + tag] = sum + bout[tag];
}

// ------------------------------- Viterbi -----------------------------------
__device__ __forceinline__ unsigned map_compose(unsigned a, unsigned b) {
  unsigned r = 0;
#pragma unroll
  for (int i = 0; i < 5; ++i) {
    const unsigned gi = (b >> (3 * i)) & 7u;
    r |= ((a >> (3 * gi)) & 7u) << (3 * i);
  }
  return r;
}

__global__ __launch_bounds__(64) void viterbi_kernel(
    const float* __restrict__ feats, const float* __restrict__ trans,
    float* __restrict__ out)
{
  __shared__ float fe[2][2560];
  __shared__ unsigned char bpb[5][T_LEN];
  const int lane = threadIdx.x;
  const int n = lane >> 3, p = lane & 7;
  const bool act = (n < 5) && (p < 5);
  const int nn = (n < 5) ? n : 0;
  const float tr = act ? trans[n * 5 + p] : -3.0e38f;
  float fvp = (p == 3) ? 0.f : -10000.f;

  for (int i = lane; i < 2560; i += 64) fe[0][i] = feats[i];
  __syncthreads();

  for (int ch = 0; ch < 8; ++ch) {
    const int buf = ch & 1;
    float pf[40];
    if (ch < 7) {
#pragma unroll
      for (int i = 0; i < 40; ++i)
        pf[i] = feats[(ch + 1) * 2560 + i * 64 + lane];
    }
    for (int tt = 0; tt < 512; ++tt) {
      const int t = ch * 512 + tt;
      float s = act ? (fvp + tr) : -3.0e38f;
      float bm = s; int bp_ = p;
#pragma unroll
      for (int d = 1; d < 8; d <<= 1) {
        const float os = __shfl_xor(bm, d, 64);
        const int   op = __shfl_xor(bp_, d, 64);
        if (os > bm || (os == bm && op < bp_)) { bm = os; bp_ = op; }
      }
      const float fvn = bm + fe[buf][tt * 5 + nn];
      if (p == 0 && n < 5) bpb[n][t] = (unsigned char)bp_;
      fvp = __shfl(fvn, p * 8, 64);
    }
    __syncthreads();
    if (ch < 7) {
#pragma unroll
      for (int i = 0; i < 40; ++i) fe[buf ^ 1][i * 64 + lane] = pf[i];
    }
    __syncthreads();
  }

  float tv = (lane < 5) ? (fvp + trans[4 * 5 + lane]) : -3.0e38f;
  int bl = lane;
#pragma unroll
  for (int d = 1; d < 8; d <<= 1) {
    const float ov = __shfl_xor(tv, d, 64);
    const int   ol = __shfl_xor(bl, d, 64);
    if (ov > tv || (ov == tv && ol < bl)) { tv = ov; bl = ol; }
  }
  const float score = __shfl(tv, 0, 64);
  const int best = __shfl(bl, 0, 64);
  if (lane == 0) out[0] = score;

  const unsigned IDENT = 0u | (1u << 3) | (2u << 6) | (3u << 9) | (4u << 12);
  const int lo = lane * 64;
  unsigned msave[64];
  unsigned comp = IDENT;
#pragma unroll
  for (int tt = 0; tt < 64; ++tt) {
    const int t = lo + tt;
    unsigned mt;
    if (t == 0) mt = IDENT;
    else
      mt = (unsigned)bpb[0][t] | ((unsigned)bpb[1][t] << 3) |
           ((unsigned)bpb[2][t] << 6) | ((unsigned)bpb[3][t] << 9) |
           ((unsigned)bpb[4][t] << 12);
    msave[tt] = mt;
    comp = map_compose(comp, mt);
  }
  unsigned inc = comp;
#pragma unroll
  for (int d = 1; d < 64; d <<= 1) {
    const unsigned other = __shfl_down(inc, d, 64);
    const unsigned comb = map_compose(inc, other);
    if (lane + d < 64) inc = comb;
  }
  unsigned exc = __shfl_down(inc, 1, 64);
  if (lane == 63) exc = IDENT;

  int y = (int)((exc >> (3 * best)) & 7u);
  out[1 + lo + 63] = (float)y;
#pragma unroll
  for (int tt = 63; tt >= 0; --tt) {
    const int t = lo + tt;
    if (t == 0) break;
    y = (int)((msave[tt] >> (3 * y)) & 7u);
    out[1 + t - 1] = (float)y;
  }
}

// ------------------------------- launcher ----------------------------------
extern "C" void kernel_launch(void* const* d_in, const int* in_sizes, int n_in,
                              void* d_out, int out_size, void* d_ws, size_t ws_size,
                              hipStream_t stream) {
  const int*   sent   = (const int*)d_in[0];
  const float* embed  = (const float*)d_in[1];
  const float* W_ih_f = (const float*)d_in[2];
  const float* W_hh_f = (const float*)d_in[3];
  const float* b_f    = (const float*)d_in[4];
  const float* W_ih_b = (const float*)d_in[5];
  const float* W_hh_b = (const float*)d_in[6];
  const float* b_b    = (const float*)d_in[7];
  const float* h0     = (const float*)d_in[8];
  const float* c0     = (const float*)d_in[9];
  const float* W_out  = (const float*)d_in[10];
  const float* b_out  = (const float*)d_in[11];
  const float* trans  = (const float*)d_in[12];

  char* ws = (char*)d_ws;
  float*          Xf    = (float*)(ws + 0);
  float*          Xb    = (float*)(ws + 33554432);
  unsigned short* xbf   = (unsigned short*)(ws + 67108864);
  unsigned short* Wfb   = (unsigned short*)(ws + 75497472);
  unsigned short* Wbb   = (unsigned short*)(ws + 79691776);
  unsigned*       hcF   = (unsigned*)(ws + 83886080);
  unsigned*       hcB   = (unsigned*)(ws + 92276736);
  float*          feats = (float*)(ws + 100667392);
  float*          out   = (float*)d_out;

  gather_kernel<<<T_LEN, 256, 0, stream>>>(sent, embed, xbf);
  convw_kernel<<<dim3(1024, 1, 2), 256, 0, stream>>>(W_ih_f, W_ih_b, Wfb, Wbb);
  inith_kernel<<<2, 512, 0, stream>>>(h0, hcF, hcB);
  gemm_x_kernel<<<dim3(32, 64, 2), 256, 0, stream>>>(xbf, Wfb, Wbb, b_f, b_b, Xf, Xb);
  lstm_kernel<<<64, 576, 0, stream>>>(W_hh_f, W_hh_b, Xf, Xb, c0, hcF, hcB);
  feats_kernel<<<T_LEN, 320, 0, stream>>>(hcF, hcB, W_out, b_out, feats);
  viterbi_kernel<<<1, 64, 0, stream>>>(feats, trans, out);
}